// Round 1
// 357.130 us; speedup vs baseline: 1.0263x; 1.0263x over previous
//
#include <hip/hip_runtime.h>
#include <hip/hip_fp16.h>

#define EPS_C   2.2204460492503131e-16f
#define NS      128
#define ND      512
#define NN      784
#define NB      128
#define BSN     (NS*NN)          // 100352
#define QM      (1.0f/784.0f)
#define LOG2E20 28.853900817779268f   // 20*log2(e): K' = exp(20*cos) = exp2(cos*this)

typedef __attribute__((ext_vector_type(8))) short bf16x8;
typedef __attribute__((ext_vector_type(4))) float f32x4;

static __device__ __forceinline__ ushort f2bf(float x) {
    uint u = __float_as_uint(x);
    uint r = (u + 0x7FFFu + ((u >> 16) & 1u)) >> 16;    // RNE
    return (ushort)r;
}
static __device__ __forceinline__ float bf2f(ushort h) {
    return __uint_as_float(((uint)h) << 16);
}
// HW packed f32->bf16 pair convert: r.lo = bf16(a), r.hi = bf16(b)
static __device__ __forceinline__ uint cvtpk_bf16(float a, float b) {
    uint r;
    asm("v_cvt_pk_bf16_f32 %0, %1, %2" : "=v"(r) : "v"(a), "v"(b));
    return r;
}

// ---------------- Kernel 1: normalize support rows, split to bf16 hi/lo ----
__global__ __launch_bounds__(128)
void tnorm_kernel(const float* __restrict__ t,
                  ushort* __restrict__ tnh, ushort* __restrict__ tnl) {
    int s = blockIdx.x, tid = threadIdx.x;
    float4 x = ((const float4*)(t + s * ND))[tid];
    float ss = x.x*x.x + x.y*x.y + x.z*x.z + x.w*x.w;
#pragma unroll
    for (int off = 1; off < 64; off <<= 1) ss += __shfl_xor(ss, off);
    __shared__ float red[2];
    if ((tid & 63) == 0) red[tid >> 6] = ss;
    __syncthreads();
    float rs = 1.0f / sqrtf(red[0] + red[1]);
    float y[4] = {x.x*rs, x.y*rs, x.z*rs, x.w*rs};
    ushort h[4], l[4];
#pragma unroll
    for (int k = 0; k < 4; k++) {
        h[k] = f2bf(y[k]);
        l[k] = f2bf(y[k] - bf2f(h[k]));
    }
    *(ushort4*)(tnh + s * ND + tid * 4) = make_ushort4(h[0], h[1], h[2], h[3]);
    *(ushort4*)(tnl + s * ND + tid * 4) = make_ushort4(l[0], l[1], l[2], l[3]);
}

// ---------------- Kernel 2: K' = exp(20*cos) via bf16x3 MFMA --------------
// Changes this round:
//  - A fragments loaded DIRECT from global (L2-resident 256 KB, shared by all
//    784 blocks): removes A staging (4 uint4 loads + 4 b128 LDS writes) and
//    8 of 16 ds_read_b128 per thread per chunk.
//  - B f32->bf16 hi/lo split via v_cvt_pk_bf16_f32 (1 instr per pair, packed
//    result directly usable); lo residual exactly compensated from returned
//    hi bits, so accuracy is independent of the HW rounding mode.
#define LDK 40   // LDS row pitch in bf16 units

__global__ void __launch_bounds__(256)
__attribute__((amdgpu_waves_per_eu(2, 4)))
gemm_k_kernel(const ushort* __restrict__ Ahi, const ushort* __restrict__ Alo,
              const float* __restrict__ f, uint* __restrict__ Kp) {
    __shared__ ushort Bsh[2][NS * LDK];
    __shared__ float  ssq_sh[128];

    const int tid  = threadIdx.x;
    const int lane = tid & 63;
    const int wid  = tid >> 6;
    const int wm   = wid & 1;
    const int wn   = wid >> 1;
    const int j0   = blockIdx.x * 128;

    const int brow  = tid >> 3;
    const int bcol4 = (tid & 7) * 4;

    const float* bPtr[4];
#pragma unroll
    for (int p = 0; p < 4; p++)
        bPtr[p] = f + (size_t)(j0 + p * 32 + brow) * ND + bcol4;

    const int mrow = lane & 15;
    const int koff = (lane >> 4) * 8;

    // A fragment base pointers (global, L2-resident). Fragment layout for
    // mfma_f32_16x16x32_bf16 A-operand: lane holds row (lane&15), 8 contiguous
    // k at (lane>>4)*8 — i.e. a 16B contiguous global load per lane.
    const ushort* aPtrH[4];
    const ushort* aPtrL[4];
#pragma unroll
    for (int i = 0; i < 4; i++) {
        int r = wm * 64 + i * 16 + mrow;
        aPtrH[i] = Ahi + (size_t)r * ND + koff;
        aPtrL[i] = Alo + (size_t)r * ND + koff;
    }

    f32x4 acc[4][4];
#pragma unroll
    for (int i = 0; i < 4; i++)
#pragma unroll
        for (int j = 0; j < 4; j++) acc[i][j] = (f32x4){0.f, 0.f, 0.f, 0.f};
    float ssqp[4] = {0.f, 0.f, 0.f, 0.f};

    // prefetch B chunk 0
    float4 bReg[4];
#pragma unroll
    for (int p = 0; p < 4; p++) bReg[p] = *(const float4*)bPtr[p];

    for (int d0 = 0; d0 < ND; d0 += 32) {
        // ---- issue A-fragment loads for THIS chunk first (no LDS dep;
        //      latency hides under conversion + barrier) ----
        bf16x8 ah[4], al[4];
#pragma unroll
        for (int i = 0; i < 4; i++) ah[i] = *(const bf16x8*)(aPtrH[i] + d0);
#pragma unroll
        for (int i = 0; i < 4; i++) al[i] = *(const bf16x8*)(aPtrL[i] + d0);

        // ---- B convert + LDS store phase ----
#pragma unroll
        for (int p = 0; p < 4; p++) {
            float4 v = bReg[p];
            ssqp[p] += v.x*v.x + v.y*v.y + v.z*v.z + v.w*v.w;
            uint hA = cvtpk_bf16(v.x, v.y);
            uint hB = cvtpk_bf16(v.z, v.w);
            float rx = v.x - __uint_as_float(hA << 16);
            float ry = v.y - __uint_as_float(hA & 0xFFFF0000u);
            float rz = v.z - __uint_as_float(hB << 16);
            float rw = v.w - __uint_as_float(hB & 0xFFFF0000u);
            uint lA = cvtpk_bf16(rx, ry);
            uint lB = cvtpk_bf16(rz, rw);
            int c = p * 32 + brow;
            *(uint2*)&Bsh[0][c * LDK + bcol4] = make_uint2(hA, hB);
            *(uint2*)&Bsh[1][c * LDK + bcol4] = make_uint2(lA, lB);
        }
        __syncthreads();
        // ---- prefetch next B chunk while MFMAs run ----
        if (d0 + 32 < ND) {
#pragma unroll
            for (int p = 0; p < 4; p++)
                bReg[p] = *(const float4*)(bPtr[p] + d0 + 32);
        }
        // ---- compute: HH, LH, then HL ----
        bf16x8 bb[4];
#pragma unroll
        for (int j = 0; j < 4; j++)
            bb[j] = *(const bf16x8*)&Bsh[0][(wn*64 + j*16 + mrow) * LDK + koff];
#pragma unroll
        for (int i = 0; i < 4; i++)
#pragma unroll
            for (int j = 0; j < 4; j++)
                acc[i][j] = __builtin_amdgcn_mfma_f32_16x16x32_bf16(ah[i], bb[j], acc[i][j], 0, 0, 0);
#pragma unroll
        for (int i = 0; i < 4; i++)
#pragma unroll
            for (int j = 0; j < 4; j++)
                acc[i][j] = __builtin_amdgcn_mfma_f32_16x16x32_bf16(al[i], bb[j], acc[i][j], 0, 0, 0);
#pragma unroll
        for (int j = 0; j < 4; j++)
            bb[j] = *(const bf16x8*)&Bsh[1][(wn*64 + j*16 + mrow) * LDK + koff];
#pragma unroll
        for (int i = 0; i < 4; i++)
#pragma unroll
            for (int j = 0; j < 4; j++)
                acc[i][j] = __builtin_amdgcn_mfma_f32_16x16x32_bf16(ah[i], bb[j], acc[i][j], 0, 0, 0);
        __syncthreads();
    }

    // ---- column-norm reduce ----
#pragma unroll
    for (int p = 0; p < 4; p++) {
#pragma unroll
        for (int off = 1; off < 8; off <<= 1) ssqp[p] += __shfl_xor(ssqp[p], off);
    }
    if ((tid & 7) == 0) {
#pragma unroll
        for (int p = 0; p < 4; p++) ssq_sh[p * 32 + (tid >> 3)] = ssqp[p];
    }
    __syncthreads();

    // ---- epilogue: K' packed for sinkhorn ----
    const int quad4 = (lane >> 4) << 2;
#pragma unroll
    for (int jt = 0; jt < 4; jt++) {
        int cloc = wn * 64 + jt * 16 + mrow;
        float rq = rsqrtf(ssq_sh[cloc]) * LOG2E20;
        int jg = j0 + cloc;
        int b2 = jg / NN;
        int nn = jg - b2 * NN;
        int jj = nn >> 6, l = nn & 63;
#pragma unroll
        for (int i = 0; i < 4; i++) {
            int s0 = wm * 64 + i * 16 + quad4;      // s0 % 4 == 0
            float k0 = exp2f(acc[i][jt][0] * rq);
            float k1 = exp2f(acc[i][jt][1] * rq);
            float k2v = exp2f(acc[i][jt][2] * rq);
            float k3 = exp2f(acc[i][jt][3] * rq);
            __half2 lo = __halves2half2(__float2half(k0), __float2half(k1));
            __half2 hi = __halves2half2(__float2half(k2v), __float2half(k3));
            size_t dw = (((size_t)(b2 * 16 + (s0 >> 3)) * 13 + jj) * 64 + l) * 4
                        + ((s0 & 7) >> 1);
            *(uint2*)(Kp + dw) = make_uint2(__builtin_bit_cast(uint, lo),
                                            __builtin_bit_cast(uint, hi));
        }
    }
}

// ---------------- Kernel 3: register-resident Sinkhorn, atomic-free -------
// 1 block/batch, 1024 thr = 16 waves. Wave w owns rows 8w..8w+7; lane l owns
// cols {l+64j}. v-reduction: per-wave partials -> LDS slab[16][784], then 784
// threads sum 16 rows each (conflict-free; no atomics, no CAS retries).
// 2 barriers/iteration: B1 publishes slab, B2 publishes v_sh AND guarantees
// slab reads done before next iteration overwrites it.
#define VSCALE 64.0f
#define PM64   (VSCALE/128.0f)
#define EPS64  (EPS_C*VSCALE)

__global__ void __launch_bounds__(1024)
__attribute__((amdgpu_waves_per_eu(4, 4)))
sinkhorn_kernel(const uint* __restrict__ Kp, float* __restrict__ Pi) {
    __shared__ float slab[16 * NN];   // 50176 B
    __shared__ float v_sh[NN];
    const int b    = blockIdx.x;
    const int tid  = threadIdx.x;
    const int lane = tid & 63;
    const int w    = tid >> 6;
    float* Pib = Pi + (size_t)b * BSN;

    // coalesced dwordx4 loads: 13 per thread
    const uint4* kbase = (const uint4*)Kp + (size_t)(b * 16 + w) * 13 * 64 + lane;
    __half2 k2[13][4];
#pragma unroll
    for (int j = 0; j < 13; j++) {
        uint4 t = kbase[j * 64];
        k2[j][0] = __builtin_bit_cast(__half2, t.x);
        k2[j][1] = __builtin_bit_cast(__half2, t.y);
        k2[j][2] = __builtin_bit_cast(__half2, t.z);
        k2[j][3] = __builtin_bit_cast(__half2, t.w);
    }
    if (lane >= 16) {   // padded tail: n = lane+768 >= 784
#pragma unroll
        for (int rp = 0; rp < 4; rp++) k2[12][rp] = __halves2half2(__half(0.f), __half(0.f));
    }

    __half2 u2[4];
    float uf[8];
#pragma unroll
    for (int rp = 0; rp < 4; rp++) u2[rp] = __halves2half2(__half(1.f), __half(1.f));
#pragma unroll
    for (int r = 0; r < 8; r++) uf[r] = 1.f;

    float* myrow = &slab[w * NN];

    for (int it = 0; it <= 10; ++it) {
        // v-pass: per-wave column partials -> private slab row (no atomics)
#pragma unroll
        for (int j = 0; j < 13; j++) {
            int n = lane + (j << 6);
            float pa = 0.f;
#pragma unroll
            for (int rp = 0; rp < 4; rp++)
                pa = __builtin_amdgcn_fdot2(k2[j][rp], u2[rp], pa, false);
            if (n < NN) myrow[n] = pa;
        }
        __syncthreads();                         // B1: slab published
        // phase 2: 784 threads each sum 16 slab rows
        if (tid < NN) {
            float s0 = 0.f, s1 = 0.f, s2 = 0.f, s3 = 0.f;
#pragma unroll
            for (int w2 = 0; w2 < 16; w2 += 4) {
                s0 += slab[(w2 + 0) * NN + tid];
                s1 += slab[(w2 + 1) * NN + tid];
                s2 += slab[(w2 + 2) * NN + tid];
                s3 += slab[(w2 + 3) * NN + tid];
            }
            v_sh[tid] = QM / (((s0 + s1) + (s2 + s3)) + EPS_C);
        }
        __syncthreads();                         // B2: v_sh ready, slab reads done
        if (it == 10) break;
        // u-pass: fp16-pair accumulate over 13 cols, 64-lane butterfly
        __half2 acc2[4];
#pragma unroll
        for (int rp = 0; rp < 4; rp++) acc2[rp] = __halves2half2(__half(0.f), __half(0.f));
#pragma unroll
        for (int j = 0; j < 13; j++) {
            int n = lane + (j << 6);
            int ni = (n < NN) ? n : 0;
            float vv = v_sh[ni] * VSCALE;
            __half vh = __float2half(vv);
            __half2 vh2 = __halves2half2(vh, vh);
#pragma unroll
            for (int rp = 0; rp < 4; rp++)
                acc2[rp] = __hfma2(vh2, k2[j][rp], acc2[rp]);   // k2==0 masks tail
        }
#pragma unroll
        for (int rp = 0; rp < 4; rp++) {
#pragma unroll
            for (int off = 1; off < 64; off <<= 1) {
                int y = __shfl_xor(__builtin_bit_cast(int, acc2[rp]), off);
                acc2[rp] = __hadd2(acc2[rp], __builtin_bit_cast(__half2, y));
            }
            float2 af = __half22float2(acc2[rp]);
            uf[2*rp]     = PM64 / (af.x + EPS64);
            uf[2*rp + 1] = PM64 / (af.y + EPS64);
            u2[rp] = __halves2half2(__float2half(uf[2*rp]), __float2half(uf[2*rp+1]));
        }
    }

    // Pi = u * K' * v'  (K'-scale cancels exactly)
#pragma unroll
    for (int j = 0; j < 13; j++) {
        int n = lane + (j << 6);
        if (n < NN) {
            float vv = v_sh[n];
#pragma unroll
            for (int rp = 0; rp < 4; rp++) {
                float2 kk = __half22float2(k2[j][rp]);
                Pib[(size_t)(8*w + 2*rp    ) * NN + n] = uf[2*rp]     * kk.x * vv;
                Pib[(size_t)(8*w + 2*rp + 1) * NN + n] = uf[2*rp + 1] * kk.y * vv;
            }
        }
    }
}

// ---------------- launcher ----------------
extern "C" void kernel_launch(void* const* d_in, const int* in_sizes, int n_in,
                              void* d_out, int out_size, void* d_ws, size_t ws_size,
                              hipStream_t stream) {
    const float* feat = (const float*)d_in[0];   // (128,28,28,512) f32
    const float* tsup = (const float*)d_in[1];   // (128,512) f32
    float* out = (float*)d_out;                  // (128,128,784) f32

    ushort* tnh = (ushort*)d_ws;                 // 128*512 bf16
    ushort* tnl = tnh + NS * ND;
    uint*   Kp  = (uint*)(tnl + NS * ND);        // 128*16*13*64*4 dwords = 27.3 MB

    tnorm_kernel<<<NS, 128, 0, stream>>>(tsup, tnh, tnl);
    gemm_k_kernel<<<(NB * NN) / 128, 256, 0, stream>>>(tnh, tnl, feat, Kp);
    sinkhorn_kernel<<<NB, 1024, 0, stream>>>(Kp, out);
}